// Round 1
// baseline (329.681 us; speedup 1.0000x reference)
//
#include <hip/hip_runtime.h>
#include <hip/hip_bf16.h>
#include <math.h>

// Problem constants
#define NHEAD 16
#define DHEAD 64
#define HIDDEN 1024
#define TSEQ 2048
#define BATCH 4
#define QKV_OUT 2112   // (2*16+1)*64
#define BT (BATCH * TSEQ)  // 8192

typedef __attribute__((ext_vector_type(8))) short bf16x8;
typedef __attribute__((ext_vector_type(4))) float floatx4;

static __device__ __forceinline__ short f2bf(float x) {
  __hip_bfloat16 h = __float2bfloat16(x);
  return *reinterpret_cast<short*>(&h);
}

#define MFMA16(a, b, c) __builtin_amdgcn_mfma_f32_16x16x32_bf16(a, b, c, 0, 0, 0)

// Async global->LDS, 16B per lane. LDS dest is wave-uniform base; data lands
// at base + lane*16B (hardware-defined), so LDS layout must be linear.
static __device__ __forceinline__ void gload_lds16(const void* g, void* l) {
  __builtin_amdgcn_global_load_lds(
      (const __attribute__((address_space(1))) void*)g,
      (__attribute__((address_space(3))) void*)l, 16, 0, 0);
}

// ---------------------------------------------------------------------------
// fp32 -> bf16 conversion, 8 elems/thread. n must be divisible by 8.
// ---------------------------------------------------------------------------
__global__ __launch_bounds__(256) void f32_to_bf16(
    const float* __restrict__ src, short* __restrict__ dst, int n) {
  const int i = (blockIdx.x * 256 + threadIdx.x) * 8;
  if (i >= n) return;
  float4 a = *(const float4*)&src[i];
  float4 b = *(const float4*)&src[i + 4];
  short o[8];
  o[0] = f2bf(a.x); o[1] = f2bf(a.y); o[2] = f2bf(a.z); o[3] = f2bf(a.w);
  o[4] = f2bf(b.x); o[5] = f2bf(b.y); o[6] = f2bf(b.z); o[7] = f2bf(b.w);
  *(uint4*)&dst[i] = *(uint4*)o;
}

// ---------------------------------------------------------------------------
// MFMA bf16 GEMM, m97 structure: C[M][N] = A[M][K] @ B[N][K]^T + bias[N].
// BM=BN=128, BK=64; 4 waves 2x2, each wave 64x64 = 4x4 16x16 frags.
// Staging via global_load_lds width=16 into linear LDS [128][64].
// N need not be a multiple of 128: staging rows clamped, stores guarded.
// M, K must be multiples of 128 / 64.
// ---------------------------------------------------------------------------
#define GBM 128
#define GBN 128
#define GBK 64

template <typename OUT_T>
__global__ __launch_bounds__(256) void gemm_bt_gll(
    const short* __restrict__ A, const short* __restrict__ B,
    const float* __restrict__ bias, OUT_T* __restrict__ C,
    int M, int N, int K) {
  __shared__ short As[GBM * GBK];
  __shared__ short Bs[GBN * GBK];

  const int tid = threadIdx.x;
  const int lane = tid & 63;
  const int wv = tid >> 6;
  const int ln = lane & 15;
  const int grp = lane >> 4;
  const int wm = wv >> 1;
  const int wn = wv & 1;
  const int rowbase = blockIdx.y * GBM;
  const int colbase = blockIdx.x * GBN;

  // staging geometry: one gload_lds call = 64 lanes x 16B = 8 rows of 64 bf16
  const int crow = lane >> 3;       // row within 8-row chunk
  const int kcol = (lane & 7) * 8;  // k-offset in shorts (16B granules)

  floatx4 acc[4][4];
#pragma unroll
  for (int m = 0; m < 4; ++m)
#pragma unroll
    for (int n = 0; n < 4; ++n) acc[m][n] = (floatx4){0.f, 0.f, 0.f, 0.f};

  for (int k0 = 0; k0 < K; k0 += GBK) {
    __syncthreads();  // previous iteration's ds_reads done
#pragma unroll
    for (int c = 0; c < 4; ++c) {
      const int tr = (wv * 4 + c) * 8 + crow;  // tile row 0..127
      gload_lds16(A + (size_t)(rowbase + tr) * K + k0 + kcol,
                  &As[(wv * 4 + c) * 8 * GBK]);
      int br = colbase + tr;
      if (br > N - 1) br = N - 1;  // clamp: OOB cols read valid memory, discarded
      gload_lds16(B + (size_t)br * K + k0 + kcol,
                  &Bs[(wv * 4 + c) * 8 * GBK]);
    }
    __syncthreads();  // compiler inserts vmcnt(0) drain before barrier

#pragma unroll
    for (int ks = 0; ks < 2; ++ks) {
      bf16x8 bfrag[4];
#pragma unroll
      for (int n = 0; n < 4; ++n)
        bfrag[n] =
            *(const bf16x8*)&Bs[(wn * 64 + n * 16 + ln) * GBK + ks * 32 + grp * 8];
#pragma unroll
      for (int m = 0; m < 4; ++m) {
        bf16x8 af =
            *(const bf16x8*)&As[(wm * 64 + m * 16 + ln) * GBK + ks * 32 + grp * 8];
#pragma unroll
        for (int n = 0; n < 4; ++n)
          acc[m][n] = MFMA16(af, bfrag[n], acc[m][n]);
      }
    }
  }

#pragma unroll
  for (int n = 0; n < 4; ++n) {
    const int col = colbase + wn * 64 + n * 16 + ln;
    if (col < N) {
      const float bv = bias[col];
#pragma unroll
      for (int m = 0; m < 4; ++m) {
#pragma unroll
        for (int r = 0; r < 4; ++r) {
          const int row = rowbase + wm * 64 + m * 16 + grp * 4 + r;
          const float v = acc[m][n][r] + bv;
          if constexpr (sizeof(OUT_T) == 2)
            C[(size_t)row * N + col] = f2bf(v);
          else
            C[(size_t)row * N + col] = v;
        }
      }
    }
  }
}

// ---------------------------------------------------------------------------
// Transpose V: vt[b][d][t] = qkv_bf16[b*T + t][2048 + d]
// ---------------------------------------------------------------------------
__global__ __launch_bounds__(256) void transpose_v(
    const short* __restrict__ qkv, short* __restrict__ vt) {
  __shared__ short tile[64][72];
  const int tt = blockIdx.x;
  const int b = blockIdx.y;
  const int tid = threadIdx.x;
  const int li = tid >> 2;
  const int lc = (tid & 3) * 16;

  const short* src = qkv + (size_t)(b * TSEQ + tt * 64 + li) * QKV_OUT + 2048 + lc;
  *(uint4*)&tile[li][lc] = *(const uint4*)src;
  *(uint4*)&tile[li][lc + 8] = *(const uint4*)(src + 8);
  __syncthreads();
  short tmp[16];
#pragma unroll
  for (int u = 0; u < 16; ++u) tmp[u] = tile[lc + u][li];
  short* dst = vt + (size_t)(b * 64 + li) * TSEQ + tt * 64 + lc;
  *(uint4*)dst = *(uint4*)&tmp[0];
  *(uint4*)(dst + 8) = *(uint4*)&tmp[8];
}

// ---------------------------------------------------------------------------
// Single-pass MFMA bf16 causal flash attention (no online max; exp scale is
// global so row-sum normalization at the end is exact).
// Block = (it, h, b): 64 q-rows, j-tiles 0..it. Longest blocks dispatch first
// (it = gridDim.x-1-blockIdx.x) so the 32-tile blocks don't straggle.
// Writes normalized attn_vec directly — no partial buffers, no combine pass.
// ---------------------------------------------------------------------------
__global__ __launch_bounds__(256) void attn_fused(
    const short* __restrict__ qkv, const short* __restrict__ vt,
    float* __restrict__ attn_vec) {
  __shared__ short Ks[64][72];  // [j][d]
  __shared__ short Vt[64][72];  // [d][j]
  __shared__ short Ps[64][72];  // [q][j], per-wave 16-row slices

  const int it = (int)gridDim.x - 1 - (int)blockIdx.x;  // 31..0, big first
  const int tid = threadIdx.x;
  const int h = blockIdx.y;
  const int b = blockIdx.z;
  const int lane = tid & 63;
  const int wv = tid >> 6;
  const int ln = lane & 15;
  const int grp = lane >> 4;
  const int qbase = wv * 16;
  const int sli = tid & 63;
  const int slc = (tid >> 6) * 16;
  const float CEXP = 0.18033688f;  // 0.125 * log2(e)

  // Q B-fragment (persistent): B[k=d][n=q]
  const short* qptr = qkv + (size_t)(b * TSEQ + it * 64 + qbase + ln) * QKV_OUT + h * 64;
  const bf16x8 bq0 = *(const bf16x8*)(qptr + grp * 8);
  const bf16x8 bq1 = *(const bf16x8*)(qptr + 32 + grp * 8);

  floatx4 oT[4];
#pragma unroll
  for (int m = 0; m < 4; ++m) oT[m] = (floatx4){0.f, 0.f, 0.f, 0.f};
  float lsum = 0.f;

  const int jend = it + 1;

  // prefetch first tile
  const short* ks0 = qkv + (size_t)(b * TSEQ + sli) * QKV_OUT + 1024 + h * 64 + slc;
  const short* vs0 = vt + (size_t)(b * 64 + sli) * TSEQ + slc;
  uint4 kr0 = *(const uint4*)ks0;
  uint4 kr1 = *(const uint4*)(ks0 + 8);
  uint4 vr0 = *(const uint4*)vs0;
  uint4 vr1 = *(const uint4*)(vs0 + 8);

  for (int jt = 0; jt < jend; ++jt) {
    __syncthreads();  // all waves done reading previous Ks/Vt
    *(uint4*)&Ks[sli][slc] = kr0;
    *(uint4*)&Ks[sli][slc + 8] = kr1;
    *(uint4*)&Vt[sli][slc] = vr0;
    *(uint4*)&Vt[sli][slc + 8] = vr1;
    __syncthreads();

    // prefetch next tile (latency hidden under compute)
    if (jt + 1 < jend) {
      const short* kn =
          qkv + (size_t)(b * TSEQ + (jt + 1) * 64 + sli) * QKV_OUT + 1024 + h * 64 + slc;
      const short* vn = vt + (size_t)(b * 64 + sli) * TSEQ + (jt + 1) * 64 + slc;
      kr0 = *(const uint4*)kn;
      kr1 = *(const uint4*)(kn + 8);
      vr0 = *(const uint4*)vn;
      vr1 = *(const uint4*)(vn + 8);
    }

    // S^T = K @ Q^T: 4 m-tiles (j), 2 k-steps (d)
    floatx4 st[4];
#pragma unroll
    for (int m = 0; m < 4; ++m) {
      bf16x8 ak0 = *(const bf16x8*)&Ks[m * 16 + ln][grp * 8];
      bf16x8 ak1 = *(const bf16x8*)&Ks[m * 16 + ln][32 + grp * 8];
      floatx4 a = (floatx4){0.f, 0.f, 0.f, 0.f};
      a = MFMA16(ak0, bq0, a);
      a = MFMA16(ak1, bq1, a);
      st[m] = a;
    }

    // causal mask on diagonal tile: j-local > q-local -> -inf
    if (jt == it) {
#pragma unroll
      for (int m = 0; m < 4; ++m)
#pragma unroll
        for (int r = 0; r < 4; ++r)
          if (m * 16 + grp * 4 + r > qbase + ln) st[m][r] = -INFINITY;
    }

    // P = exp2(CEXP * s), accumulate l, packed bf16x4 store to Ps
#pragma unroll
    for (int m = 0; m < 4; ++m) {
      float p0 = exp2f(CEXP * st[m][0]);
      float p1 = exp2f(CEXP * st[m][1]);
      float p2 = exp2f(CEXP * st[m][2]);
      float p3 = exp2f(CEXP * st[m][3]);
      lsum += (p0 + p1) + (p2 + p3);
      short pk[4] = {f2bf(p0), f2bf(p1), f2bf(p2), f2bf(p3)};
      *(uint2*)&Ps[qbase + ln][m * 16 + grp * 4] = *(uint2*)pk;
    }

    // O^T += V^T(A) @ P^T(B)  (same-wave LDS write->read, in-order DS)
    bf16x8 bp0 = *(const bf16x8*)&Ps[qbase + ln][grp * 8];
    bf16x8 bp1 = *(const bf16x8*)&Ps[qbase + ln][32 + grp * 8];
#pragma unroll
    for (int m = 0; m < 4; ++m) {
      bf16x8 av0 = *(const bf16x8*)&Vt[m * 16 + ln][grp * 8];
      bf16x8 av1 = *(const bf16x8*)&Vt[m * 16 + ln][32 + grp * 8];
      oT[m] = MFMA16(av0, bp0, oT[m]);
      oT[m] = MFMA16(av1, bp1, oT[m]);
    }
  }

  // reduce l across grp (lanes with same ln share q)
  lsum += __shfl_xor(lsum, 16);
  lsum += __shfl_xor(lsum, 32);

  const float inv = 1.f / lsum;
  float* orow =
      attn_vec + ((size_t)(b * NHEAD + h) * TSEQ + it * 64 + qbase + ln) * DHEAD;
#pragma unroll
  for (int m = 0; m < 4; ++m) {
    float4 o4;
    o4.x = oT[m][0] * inv;
    o4.y = oT[m][1] * inv;
    o4.z = oT[m][2] * inv;
    o4.w = oT[m][3] * inv;
    *(float4*)&orow[m * 16 + grp * 4] = o4;
  }
}

// ---------------------------------------------------------------------------
// Mean over heads -> bf16 (feeds the MFMA out-projection). 2 elems/thread.
// ---------------------------------------------------------------------------
__global__ __launch_bounds__(256) void mean_heads(
    const float* __restrict__ attn_vec, short* __restrict__ m) {
  const int gid = blockIdx.x * 256 + threadIdx.x;  // over BT*64/2
  const int d2 = (gid & 31) * 2;
  const int t = (gid >> 5) & (TSEQ - 1);
  const int b = gid >> 16;
  float s0 = 0.f, s1 = 0.f;
#pragma unroll
  for (int h = 0; h < NHEAD; ++h) {
    const float* p = &attn_vec[(((size_t)(b * NHEAD + h) * TSEQ) + t) * DHEAD + d2];
    s0 += p[0];
    s1 += p[1];
  }
  short pk[2] = {f2bf(s0 * (1.f / 16.f)), f2bf(s1 * (1.f / 16.f))};
  *(uint*)&m[gid * 2] = *(uint*)pk;
}

// ---------------------------------------------------------------------------
extern "C" void kernel_launch(void* const* d_in, const int* in_sizes, int n_in,
                              void* d_out, int out_size, void* d_ws, size_t ws_size,
                              hipStream_t stream) {
  const float* x     = (const float*)d_in[0];  // [4,2048,1024]
  const float* w_qkv = (const float*)d_in[1];  // [2112,1024]
  const float* b_qkv = (const float*)d_in[2];  // [2112]
  const float* w_out = (const float*)d_in[3];  // [1024,64]
  const float* b_out = (const float*)d_in[4];  // [1024]

  float* out      = (float*)d_out;              // [4,2048,1024]
  float* attn_vec = out + (size_t)BT * HIDDEN;  // [4,16,2048,64]

  // Workspace layout (all bf16; no fp32 partial buffers anymore)
  short* qkv_bf  = (short*)d_ws;                           // [8192][2112]
  short* vt_bf   = qkv_bf + (size_t)BT * QKV_OUT;          // [4][64][2048]
  short* wout_bf = vt_bf + (size_t)BATCH * DHEAD * TSEQ;   // [1024][64]
  short* m_attn  = wout_bf + (size_t)HIDDEN * DHEAD;       // [8192][64]
  short* x_bf    = m_attn + (size_t)BT * DHEAD;            // [8192][1024]
  short* w_bf    = x_bf + (size_t)BT * HIDDEN;             // [2112][1024]

  // 0. convert inputs to bf16
  f32_to_bf16<<<dim3(BT * HIDDEN / 8 / 256), 256, 0, stream>>>(
      x, x_bf, BT * HIDDEN);
  f32_to_bf16<<<dim3(QKV_OUT * HIDDEN / 8 / 256), 256, 0, stream>>>(
      w_qkv, w_bf, QKV_OUT * HIDDEN);
  f32_to_bf16<<<dim3(HIDDEN * DHEAD / 8 / 256), 256, 0, stream>>>(
      w_out, wout_bf, HIDDEN * DHEAD);

  // 1. qkv = x @ w_qkv^T + b_qkv  (m97-style MFMA, 17th col-tile partial)
  gemm_bt_gll<short><<<dim3((QKV_OUT + GBN - 1) / GBN, BT / GBM), 256, 0, stream>>>(
      x_bf, w_bf, b_qkv, qkv_bf, BT, QKV_OUT, HIDDEN);

  // 2. pre-transpose V: vt[b][d][t]
  transpose_v<<<dim3(TSEQ / 64, BATCH), 256, 0, stream>>>(qkv_bf, vt_bf);

  // 3. single-pass MFMA causal flash attention
  attn_fused<<<dim3(TSEQ / 64, NHEAD, BATCH), 256, 0, stream>>>(
      qkv_bf, vt_bf, attn_vec);

  // 4. mean over heads -> bf16
  mean_heads<<<dim3(BT * DHEAD / 2 / 256), 256, 0, stream>>>(attn_vec, m_attn);

  // 5. out = m_attn @ w_out^T + b_out  (fp32 out)
  gemm_bt_gll<float><<<dim3(HIDDEN / GBN, BT / GBM), 256, 0, stream>>>(
      m_attn, wout_bf, b_out, out, BT, HIDDEN, DHEAD);
}